// Round 10
// baseline (2174.580 us; speedup 1.0000x reference)
//
#include <hip/hip_runtime.h>

#define TT 4000   // timesteps
#define HH 64     // hidden
#define NB 256    // batch
#define EE 128    // fc out

typedef __attribute__((ext_vector_type(2))) _Float16 h2;
typedef __attribute__((ext_vector_type(8))) _Float16 h8;

__device__ __forceinline__ float ftanh(float x) {
    return fmaf(2.f, __builtin_amdgcn_rcpf(1.f + __expf(-2.f * x)), -1.f);
}

#if __has_builtin(__builtin_amdgcn_fdot2)
#define FDOT2(a, b, c) __builtin_amdgcn_fdot2((a), (b), (c), false)
#else
#define FDOT2(a, b, c) fmaf((float)(a).x, (float)(b).x, fmaf((float)(a).y, (float)(b).y, (c)))
#endif

// h2 sub-extract from h8 register (sub-register addressing, no memory).
#define H2V(V, i) (__builtin_shufflevector((V), (V), 2 * (i), 2 * (i) + 1))

// Quad broadcast via DPP quad_perm (VALU pipe): ctrl [s,s,s,s].
#define DPPQ(v, ctrl) __int_as_float(__builtin_amdgcn_update_dpp( \
    0, __float_as_int(v), (ctrl), 0xF, 0xF, true))

// Load one float4 -> two named h2 (straight-line, SROA-safe).
#define LD4(P, O, N0, N1) \
    h2 N0, N1; { float4 _t = (P)[O]; \
      N0 = h2{(_Float16)_t.x, (_Float16)_t.y}; \
      N1 = h2{(_Float16)_t.z, (_Float16)_t.w}; }

#define DOT8(W0, W1, W2, W3, H, ACC) \
    ACC = FDOT2(W0, H2V(H, 0), ACC); ACC = FDOT2(W1, H2V(H, 1), ACC); \
    ACC = FDOT2(W2, H2V(H, 2), ACC); ACC = FDOT2(W3, H2V(H, 3), ACC);

// One block (256 thr = 4 waves) per batch element. tid = 4n + j:
//   n = h-index 0..63, j = gate (0:i 1:f 2:g 3:o). Lane owns gate row (j,n)
//   of BOTH layers with the FULL k=64 (96 named h2 weights + remat fence).
//
// R9 post-mortem: the binding resource is the DS pipe (~900 cyc/step/CU at 8
// waves: 64 b128 h-broadcast reads [layout-invariant] + 16 ds_swizzle +
// writes), not VALU (676 cyc, 54% busy). This layout removes every DS op
// that scales with wave count: no reduction butterfly (full-k rows), gate
// gather = pure quad DPP, cell update redundant across the quad (c0/c1 valid
// in all lanes), j==0/j==1 lanes write h0/h1. DS/step: ~70 instr vs ~96.
// VALU/SIMD: 1 wave x ~135 instr — far under the DS floor.
//
// Layer pipelining (verified R3-R9): iter t computes L0 gates(t) from h0(t-1)
// and L1 gates(t-1) from {h1(t-2), h0(t-1)}. 1 barrier/step, h double-buffered.
__global__ __launch_bounds__(256, 1)
void lstm2_fc_kernel(const float* __restrict__ x,      // [B, T, 1]
                     const float* __restrict__ W_ih0,  // [256, 1]
                     const float* __restrict__ W_hh0,  // [256, 64]
                     const float* __restrict__ b_ih0,  // [256]
                     const float* __restrict__ b_hh0,  // [256]
                     const float* __restrict__ W_ih1,  // [256, 64]
                     const float* __restrict__ W_hh1,  // [256, 64]
                     const float* __restrict__ b_ih1,  // [256]
                     const float* __restrict__ b_hh1,  // [256]
                     const float* __restrict__ W_fc,   // [128, 64]
                     const float* __restrict__ b_fc,   // [128]
                     float* __restrict__ out)          // [B, 128]
{
    const int b   = blockIdx.x;
    const int tid = threadIdx.x;    // 0..255
    const int n   = tid >> 2;       // h-index 0..63
    const int jj  = tid & 3;        // gate

    __shared__ float x_s[TT];                          // 16 KB
    __shared__ __align__(16) _Float16 hbuf[2][2 * HH]; // [parity][h0|h1], fp16

    for (int t = tid; t < TT; t += 256) x_s[t] = x[(size_t)b * TT + t];
    ((_Float16*)hbuf)[tid] = (_Float16)0.f;            // 256 entries, all threads

    const int row = jj * HH + n;    // gate row in [0,256)
    const float4* p0 = (const float4*)(W_hh0 + row * HH);   // 16 float4
    const float4* p1 = (const float4*)(W_ih1 + row * HH);
    const float4* p2 = (const float4*)(W_hh1 + row * HH);

    LD4(p0, 0,  A0,  A1)  LD4(p0, 1,  A2,  A3)  LD4(p0, 2,  A4,  A5)  LD4(p0, 3,  A6,  A7)
    LD4(p0, 4,  A8,  A9)  LD4(p0, 5,  A10, A11) LD4(p0, 6,  A12, A13) LD4(p0, 7,  A14, A15)
    LD4(p0, 8,  A16, A17) LD4(p0, 9,  A18, A19) LD4(p0, 10, A20, A21) LD4(p0, 11, A22, A23)
    LD4(p0, 12, A24, A25) LD4(p0, 13, A26, A27) LD4(p0, 14, A28, A29) LD4(p0, 15, A30, A31)
    LD4(p1, 0,  B0,  B1)  LD4(p1, 1,  B2,  B3)  LD4(p1, 2,  B4,  B5)  LD4(p1, 3,  B6,  B7)
    LD4(p1, 4,  B8,  B9)  LD4(p1, 5,  B10, B11) LD4(p1, 6,  B12, B13) LD4(p1, 7,  B14, B15)
    LD4(p1, 8,  B16, B17) LD4(p1, 9,  B18, B19) LD4(p1, 10, B20, B21) LD4(p1, 11, B22, B23)
    LD4(p1, 12, B24, B25) LD4(p1, 13, B26, B27) LD4(p1, 14, B28, B29) LD4(p1, 15, B30, B31)
    LD4(p2, 0,  C0,  C1)  LD4(p2, 1,  C2,  C3)  LD4(p2, 2,  C4,  C5)  LD4(p2, 3,  C6,  C7)
    LD4(p2, 4,  C8,  C9)  LD4(p2, 5,  C10, C11) LD4(p2, 6,  C12, C13) LD4(p2, 7,  C14, C15)
    LD4(p2, 8,  C16, C17) LD4(p2, 9,  C18, C19) LD4(p2, 10, C20, C21) LD4(p2, 11, C22, C23)
    LD4(p2, 12, C24, C25) LD4(p2, 13, C26, C27) LD4(p2, 14, C28, C29) LD4(p2, 15, C30, C31)

    float wx  = W_ih0[row];
    float bb0 = b_ih0[row] + b_hh0[row];
    float bb1 = b_ih1[row] + b_hh1[row];

    // Remat fences (R7/R9-proven; <=27 operands each).
    asm volatile("" : "+v"(A0),"+v"(A1),"+v"(A2),"+v"(A3),"+v"(A4),"+v"(A5),
                      "+v"(A6),"+v"(A7),"+v"(A8),"+v"(A9),"+v"(A10),"+v"(A11),
                      "+v"(A12),"+v"(A13),"+v"(A14),"+v"(A15),"+v"(A16),"+v"(A17),
                      "+v"(A18),"+v"(A19),"+v"(A20),"+v"(A21),"+v"(A22),"+v"(A23));
    asm volatile("" : "+v"(A24),"+v"(A25),"+v"(A26),"+v"(A27),"+v"(A28),"+v"(A29),
                      "+v"(A30),"+v"(A31),"+v"(B0),"+v"(B1),"+v"(B2),"+v"(B3),
                      "+v"(B4),"+v"(B5),"+v"(B6),"+v"(B7),"+v"(B8),"+v"(B9),
                      "+v"(B10),"+v"(B11),"+v"(B12),"+v"(B13),"+v"(B14),"+v"(B15));
    asm volatile("" : "+v"(B16),"+v"(B17),"+v"(B18),"+v"(B19),"+v"(B20),"+v"(B21),
                      "+v"(B22),"+v"(B23),"+v"(B24),"+v"(B25),"+v"(B26),"+v"(B27),
                      "+v"(B28),"+v"(B29),"+v"(B30),"+v"(B31),"+v"(C0),"+v"(C1),
                      "+v"(C2),"+v"(C3),"+v"(C4),"+v"(C5),"+v"(C6),"+v"(C7));
    asm volatile("" : "+v"(C8),"+v"(C9),"+v"(C10),"+v"(C11),"+v"(C12),"+v"(C13),
                      "+v"(C14),"+v"(C15),"+v"(C16),"+v"(C17),"+v"(C18),"+v"(C19),
                      "+v"(C20),"+v"(C21),"+v"(C22),"+v"(C23),"+v"(C24),"+v"(C25),
                      "+v"(C26),"+v"(C27),"+v"(C28),"+v"(C29),"+v"(C30),"+v"(C31),
                      "+v"(wx),"+v"(bb0),"+v"(bb1));

    // Branchless activation constants: act(z) = mm * rcp(1 + exp(kk*z)) + aa.
    const bool isg = (jj == 2);
    const float kk = isg ? -2.f : -1.f;
    const float mm = isg ?  2.f :  1.f;
    const float aa = isg ? -1.f :  0.f;

    float c0 = 0.f, c1 = 0.f;   // valid in ALL lanes (redundant quad compute)

    __syncthreads();

    for (int t = 0; t <= TT; ++t) {
        const float xt = x_s[(t < TT) ? t : 0];
        const h8* hb = (const h8*)hbuf[t & 1];
        // Full h0 (8x b128) and h1 (8x b128), wave-uniform broadcast reads.
        h8 Ha0 = hb[0], Ha1 = hb[1], Ha2 = hb[2], Ha3 = hb[3];
        h8 Ha4 = hb[4], Ha5 = hb[5], Ha6 = hb[6], Ha7 = hb[7];
        h8 Hb0 = hb[8], Hb1 = hb[9], Hb2 = hb[10], Hb3 = hb[11];
        h8 Hb4 = hb[12], Hb5 = hb[13], Hb6 = hb[14], Hb7 = hb[15];

        float acc0 = fmaf(xt, wx, bb0);   // L0 row (j,n), time t
        float a1a  = bb1;                 // W_ih1 . h0(t-1)
        float a1b  = 0.f;                 // W_hh1 . h1(t-2)

        DOT8(A0,  A1,  A2,  A3,  Ha0, acc0) DOT8(A4,  A5,  A6,  A7,  Ha1, acc0)
        DOT8(A8,  A9,  A10, A11, Ha2, acc0) DOT8(A12, A13, A14, A15, Ha3, acc0)
        DOT8(A16, A17, A18, A19, Ha4, acc0) DOT8(A20, A21, A22, A23, Ha5, acc0)
        DOT8(A24, A25, A26, A27, Ha6, acc0) DOT8(A28, A29, A30, A31, Ha7, acc0)

        DOT8(B0,  B1,  B2,  B3,  Ha0, a1a)  DOT8(B4,  B5,  B6,  B7,  Ha1, a1a)
        DOT8(B8,  B9,  B10, B11, Ha2, a1a)  DOT8(B12, B13, B14, B15, Ha3, a1a)
        DOT8(B16, B17, B18, B19, Ha4, a1a)  DOT8(B20, B21, B22, B23, Ha5, a1a)
        DOT8(B24, B25, B26, B27, Ha6, a1a)  DOT8(B28, B29, B30, B31, Ha7, a1a)

        DOT8(C0,  C1,  C2,  C3,  Hb0, a1b)  DOT8(C4,  C5,  C6,  C7,  Hb1, a1b)
        DOT8(C8,  C9,  C10, C11, Hb2, a1b)  DOT8(C12, C13, C14, C15, Hb3, a1b)
        DOT8(C16, C17, C18, C19, Hb4, a1b)  DOT8(C20, C21, C22, C23, Hb5, a1b)
        DOT8(C24, C25, C26, C27, Hb6, a1b)  DOT8(C28, C29, C30, C31, Hb7, a1b)

        float acc1 = a1a + a1b;

        // Per-lane activations for its L0 row and L1 row.
        float e0 = __expf(kk * acc0);
        float act0 = fmaf(mm, __builtin_amdgcn_rcpf(1.f + e0), aa);
        float e1 = __expf(kk * acc1);
        float act1 = fmaf(mm, __builtin_amdgcn_rcpf(1.f + e1), aa);

        // Quad gather (pure DPP): all lanes get i,f,g,o of their n.
        float i0 = DPPQ(act0, 0x00), f0 = DPPQ(act0, 0x55);
        float g0 = DPPQ(act0, 0xAA), o0 = DPPQ(act0, 0xFF);
        float i1 = DPPQ(act1, 0x00), f1 = DPPQ(act1, 0x55);
        float g1 = DPPQ(act1, 0xAA), o1 = DPPQ(act1, 0xFF);

        if (t < TT) {                      // L0 cell (time t), uniform branch
            c0 = fmaf(f0, c0, i0 * g0);
            float hn = o0 * ftanh(c0);
            if (jj == 0) hbuf[(t + 1) & 1][n] = (_Float16)hn;
        }
        if (t > 0) {                       // L1 cell (time t-1)
            c1 = fmaf(f1, c1, i1 * g1);
            float hn = o1 * ftanh(c1);
            if (jj == 1) hbuf[(t + 1) & 1][HH + n] = (_Float16)hn;
        }
        __syncthreads();                   // h exchange (double-buffered)
    }

    // FC on final h1 = h1(TT-1), in hbuf[(TT+1)&1][64..128).
    if (tid < EE) {
        const _Float16* h1f = &hbuf[(TT + 1) & 1][HH];
        float acc = b_fc[tid];
        const float4* wf = (const float4*)(W_fc + tid * HH);
        #pragma unroll
        for (int k = 0; k < HH / 4; ++k) {
            float4 v = wf[k];
            acc = fmaf(v.x, (float)h1f[4*k+0], acc);
            acc = fmaf(v.y, (float)h1f[4*k+1], acc);
            acc = fmaf(v.z, (float)h1f[4*k+2], acc);
            acc = fmaf(v.w, (float)h1f[4*k+3], acc);
        }
        out[(size_t)b * EE + tid] = acc;
    }
}

extern "C" void kernel_launch(void* const* d_in, const int* in_sizes, int n_in,
                              void* d_out, int out_size, void* d_ws, size_t ws_size,
                              hipStream_t stream) {
    const float* x     = (const float*)d_in[0];
    const float* W_ih0 = (const float*)d_in[1];
    const float* W_hh0 = (const float*)d_in[2];
    const float* b_ih0 = (const float*)d_in[3];
    const float* b_hh0 = (const float*)d_in[4];
    const float* W_ih1 = (const float*)d_in[5];
    const float* W_hh1 = (const float*)d_in[6];
    const float* b_ih1 = (const float*)d_in[7];
    const float* b_hh1 = (const float*)d_in[8];
    const float* W_fc  = (const float*)d_in[9];
    const float* b_fc  = (const float*)d_in[10];
    float* out = (float*)d_out;

    lstm2_fc_kernel<<<dim3(NB), dim3(256), 0, stream>>>(
        x, W_ih0, W_hh0, b_ih0, b_hh0, W_ih1, W_hh1, b_ih1, b_hh1, W_fc, b_fc, out);
}